// Round 8
// baseline (181.797 us; speedup 1.0000x reference)
//
#include <hip/hip_runtime.h>
#include <stdint.h>

namespace {

constexpr int Bb = 8, Ll = 6, Dd = 256, Pp = 1024;
constexpr float SCALE_Y = 14.285714285714286f * 1.4426950408889634f; // (1/0.07)*log2(e)
constexpr float M0y = 21.0f;   // > max |y| = 20.61
constexpr float LN2f = 0.6931471805599453f;

typedef __attribute__((ext_vector_type(8))) short short8;
typedef __attribute__((ext_vector_type(4))) float floatx4;

// upper-triangular tile pairs (pt<=qt), encoded pt*16+qt
__device__ const int PAIRS[36] = {
  0x00,0x01,0x02,0x03,0x04,0x05,0x06,0x07,
  0x11,0x12,0x13,0x14,0x15,0x16,0x17,
  0x22,0x23,0x24,0x25,0x26,0x27,
  0x33,0x34,0x35,0x36,0x37,
  0x44,0x45,0x46,0x47,
  0x55,0x56,0x57,
  0x66,0x67,
  0x77
};

// ---------------- JAX threefry2x32 (key = (0, 42)), bit-exact ----------------
__device__ __forceinline__ uint32_t rotl32(uint32_t x, int n) {
  return (x << n) | (x >> (32 - n));
}
__device__ __forceinline__ void tf_round(uint32_t& x0, uint32_t& x1, int r) {
  x0 += x1; x1 = rotl32(x1, r); x1 ^= x0;
}
__device__ void threefry2x32(uint32_t x0, uint32_t x1, uint32_t& o0, uint32_t& o1) {
  const uint32_t k0 = 0u, k1 = 42u;
  const uint32_t k2 = k0 ^ k1 ^ 0x1BD11BDAu;
  x0 += k0; x1 += k1;
  tf_round(x0,x1,13); tf_round(x0,x1,15); tf_round(x0,x1,26); tf_round(x0,x1,6);
  x0 += k1; x1 += k2 + 1u;
  tf_round(x0,x1,17); tf_round(x0,x1,29); tf_round(x0,x1,16); tf_round(x0,x1,24);
  x0 += k2; x1 += k0 + 2u;
  tf_round(x0,x1,13); tf_round(x0,x1,15); tf_round(x0,x1,26); tf_round(x0,x1,6);
  x0 += k0; x1 += k1 + 3u;
  tf_round(x0,x1,17); tf_round(x0,x1,29); tf_round(x0,x1,16); tf_round(x0,x1,24);
  x0 += k1; x1 += k2 + 4u;
  tf_round(x0,x1,13); tf_round(x0,x1,15); tf_round(x0,x1,26); tf_round(x0,x1,6);
  x0 += k2; x1 += k0 + 5u;
  o0 = x0; o1 = x1;
}
__device__ float jax_u01(uint32_t idx) {
  const uint32_t HALF = (uint32_t)(Bb * Ll * Pp / 2); // 24576
  uint32_t o0, o1, bits;
  if (idx < HALF) { threefry2x32(idx, idx + HALF, o0, o1); bits = o0; }
  else            { threefry2x32(idx - HALF, idx, o0, o1); bits = o1; }
  return __uint_as_float((bits >> 9) | 0x3f800000u) - 1.0f;
}

__device__ __forceinline__ unsigned short bf16rne(float x) {
  uint32_t u = __float_as_uint(x);
  return (unsigned short)((u + 0x7FFFu + ((u >> 16) & 1u)) >> 16);
}
__device__ __forceinline__ float bf16tof(unsigned short h) {
  return __uint_as_float(((uint32_t)h) << 16);
}

// ---------------- fused prep kernel (block-range dispatch) ----------------
constexpr int NB_NORM = Bb * Pp * Ll / 4;  // 12288
constexpr int NB_ROW  = Bb * Pp / 4;       // 2048

__global__ void prep_k(const float* __restrict__ meta, const int* __restrict__ thing,
                       const int* __restrict__ label, unsigned short* __restrict__ wn,
                       int* __restrict__ qpos, int* __restrict__ negc,
                       int* __restrict__ qidx, int* __restrict__ Kv,
                       int* __restrict__ gatev, float* __restrict__ rowsum_g,
                       float* __restrict__ out) {
  __shared__ int sK[256], sG[256];
  const int bid = blockIdx.x, t = threadIdx.x;

  if (bid < NB_NORM) {
    // ---- normalize + bf16 ----
    const int wid = (bid * 256 + t) >> 6;   // (b*P+p)*L+l
    const int lane = t & 63;
    const float4 v = *(const float4*)(meta + (size_t)wid * Dd + lane * 4);
    float ss = v.x * v.x + v.y * v.y + v.z * v.z + v.w * v.w;
    #pragma unroll
    for (int m = 32; m; m >>= 1) ss += __shfl_xor(ss, m, 64);
    const float inv = 1.0f / fmaxf(sqrtf(ss), 1e-12f);
    const int bp = wid / Ll, l = wid - bp * Ll;
    const int b = bp >> 10, p = bp & (Pp - 1);
    unsigned short* dst = wn + ((size_t)(b * Ll + l) * Pp + p) * Dd + lane * 4;
    ushort4 o;
    o.x = bf16rne(v.x * inv); o.y = bf16rne(v.y * inv);
    o.z = bf16rne(v.z * inv); o.w = bf16rne(v.w * inv);
    *(ushort4*)dst = o;
    return;
  }
  if (bid < NB_NORM + NB_ROW) {
    // ---- row stats: one wave per (b,p) ----
    const int wid = (bid - NB_NORM) * 4 + (t >> 6);
    const int lane = t & 63;
    const int b = wid >> 10, p = wid & (Pp - 1);
    const int* lab = label + b * Pp;
    const int* th  = thing + b * Pp;
    const int myLab = lab[p];
    const bool myValid = (th[p] != 0);

    uint32_t posbits = 0;
    int cnt[16];
    int pc = 0, nc = 0, last = -1;
    #pragma unroll
    for (int c = 0; c < 16; ++c) {
      const int q = c * 64 + lane;
      const int lq = lab[q];
      const bool vq = (th[q] != 0);
      const bool same = (lq == myLab);
      const bool pos = myValid && vq && same && (q != p);
      const bool neg = myValid && vq && !same;
      uint64_t bp2 = __ballot(pos);
      uint64_t bn = __ballot(neg);
      if (pos) posbits |= (1u << c);
      cnt[c] = __popcll(bp2);
      pc += cnt[c];
      nc += __popcll(bn);
      if (bn) last = c * 64 + 63 - __clzll(bn);
    }
    int qsel[Ll];
    #pragma unroll
    for (int l = 0; l < Ll; ++l) qsel[l] = p;
    if (pc > 0) {
      for (int l = 0; l < Ll; ++l) {
        const float u = jax_u01((uint32_t)((b * Ll + l) * Pp + p));
        int r = (int)floorf(u * (float)pc);
        r = min(r, pc - 1);
        int base = 0;
        for (int c = 0; c < 16; ++c) {
          if (r < base + cnt[c]) {
            const bool mine = (posbits >> c) & 1u;
            uint64_t bm = __ballot(mine);
            uint64_t ltmask = (lane == 0) ? 0ull : (~0ull >> (64 - lane));
            int myrank = __popcll(bm & ltmask);
            bool hit = mine && (base + myrank == r);
            uint64_t hb = __ballot(hit);
            qsel[l] = c * 64 + (int)__builtin_ctzll(hb);
            break;
          }
          base += cnt[c];
        }
      }
    }
    if (lane == 0) {
      negc[wid] = nc;
      qidx[wid] = (last < 0) ? 0 : last;
      #pragma unroll
      for (int l = 0; l < Ll; ++l) qpos[(b * Ll + l) * Pp + p] = qsel[l];
    }
    return;
  }
  if (bid < NB_NORM + NB_ROW + Bb) {
    // ---- batch stats ----
    const int b = bid - (NB_NORM + NB_ROW);
    int k = 0;
    for (int p = t; p < Pp; p += 256) k += (thing[b * Pp + p] != 0);
    int g = 0;
    if (t < 128) {
      int any = 0;
      for (int tt = 0; tt < 8; ++tt) any |= (thing[(b * 128 + t) * 8 + tt] != 0);
      g = any;
    }
    sK[t] = k; sG[t] = g;
    __syncthreads();
    for (int s = 128; s; s >>= 1) {
      if (t < s) { sK[t] += sK[t + s]; sG[t] += sG[t + s]; }
      __syncthreads();
    }
    if (t == 0) { Kv[b] = sK[0]; gatev[b] = (sG[0] >= 2) ? 1 : 0; }
    return;
  }
  if (bid < NB_NORM + NB_ROW + Bb + 48) {
    // ---- zero rowsum_g ----
    const int idx = (bid - (NB_NORM + NB_ROW + Bb)) * 256 + t;
    *(float4*)(rowsum_g + idx * 4) = (float4){0.f, 0.f, 0.f, 0.f};
    return;
  }
  if (t == 0) out[0] = 0.f;
}

// ---------------- zp/zl via direct dots (one wave per (bl,p)) ----------------
__global__ void zpzl_k(const unsigned short* __restrict__ wn,
                       const int* __restrict__ qpos, const int* __restrict__ qidx,
                       float* __restrict__ zp_g, float* __restrict__ zl_g) {
  const int wid = blockIdx.x * 4 + (threadIdx.x >> 6);  // bl*1024+p
  const int lane = threadIdx.x & 63;
  const int bl = wid >> 10, p = wid & (Pp - 1);
  const int b = bl / Ll;
  const int qp = qpos[bl * Pp + p];
  const int qi = qidx[b * Pp + p];
  const unsigned short* W = wn + (size_t)bl * Pp * Dd;
  const ushort4 a  = *(const ushort4*)(W + (size_t)p  * Dd + lane * 4);
  const ushort4 vb = *(const ushort4*)(W + (size_t)qp * Dd + lane * 4);
  const ushort4 vc = *(const ushort4*)(W + (size_t)qi * Dd + lane * 4);
  const float ax = bf16tof(a.x), ay = bf16tof(a.y), az = bf16tof(a.z), aw = bf16tof(a.w);
  float sp = ax * bf16tof(vb.x) + ay * bf16tof(vb.y) + az * bf16tof(vb.z) + aw * bf16tof(vb.w);
  float sl = ax * bf16tof(vc.x) + ay * bf16tof(vc.y) + az * bf16tof(vc.z) + aw * bf16tof(vc.w);
  #pragma unroll
  for (int m = 32; m; m >>= 1) {
    sp += __shfl_xor(sp, m, 64);
    sl += __shfl_xor(sl, m, 64);
  }
  if (lane == 0) {
    zp_g[bl * Pp + p] = sp * SCALE_Y;
    zl_g[bl * Pp + p] = sl * SCALE_Y;
  }
}

// ---------------- MFMA Gram, upper-tri pairs, DIRECT-FROM-L2 fragments ----------------
// No LDS staging, no K-loop barriers: per-(b,l) operand slab is 512 KB (L2-resident,
// re-read by all 36 blocks of the slab). Fragment loads are 16 rows x 64 B fully-used
// cache lines, `sub` folds into the 13-bit immediate offset (zero K-loop VALU).
// k-accumulation order identical to r7 (sub*32 <-> (k0,sub) order) -> bitwise-same result.
__global__ __launch_bounds__(256)
void gemm_loss_k(const unsigned short* __restrict__ wn,
                 const int* __restrict__ thing, const int* __restrict__ label,
                 float* __restrict__ rowsum_g) {
  __shared__ int labp_s[128], valp_s[128], labq_s[128], valq_s[128];
  __shared__ float rowsum_lds[128], colsum_lds[128];

  const int t = threadIdx.x;
  const int bl = blockIdx.y;
  const int b = bl / Ll;
  const int pair = PAIRS[blockIdx.x];
  const int pt = pair >> 4, qt = pair & 15;
  const bool diag = (pt == qt);
  const int p0 = pt * 128, q0 = qt * 128;

  if (t < 128) {
    labp_s[t] = label[b * Pp + p0 + t];
    valp_s[t] = thing[b * Pp + p0 + t];
    labq_s[t] = label[b * Pp + q0 + t];
    valq_s[t] = thing[b * Pp + q0 + t];
    rowsum_lds[t] = 0.f;
    colsum_lds[t] = 0.f;
  }
  __syncthreads();

  const unsigned short* Wbl = wn + (size_t)bl * Pp * Dd;
  const int lane = t & 63;
  const int w = t >> 6, wr = w >> 1, wc = w & 1;
  const int cq = lane & 15, rq = lane >> 4;

  // per-lane fragment base pointers: row (..+cq)*Dd, k-chunk rq*8 halves
  const unsigned short* Ap[4];
  const unsigned short* Bp[4];
  #pragma unroll
  for (int f = 0; f < 4; ++f) {
    Ap[f] = Wbl + (size_t)(p0 + wr * 64 + f * 16 + cq) * Dd + rq * 8;
    Bp[f] = Wbl + (size_t)(q0 + wc * 64 + f * 16 + cq) * Dd + rq * 8;
  }

  floatx4 acc[4][4];
  #pragma unroll
  for (int i = 0; i < 4; ++i)
    #pragma unroll
    for (int j = 0; j < 4; ++j) acc[i][j] = (floatx4){0.f, 0.f, 0.f, 0.f};

  #pragma unroll
  for (int sub = 0; sub < 8; ++sub) {       // k = sub*32 .. sub*32+31
    short8 af[4], bf[4];
    #pragma unroll
    for (int fi = 0; fi < 4; ++fi) af[fi] = *(const short8*)(Ap[fi] + sub * 32);
    #pragma unroll
    for (int fj = 0; fj < 4; ++fj) bf[fj] = *(const short8*)(Bp[fj] + sub * 32);
    #pragma unroll
    for (int fi = 0; fi < 4; ++fi)
      #pragma unroll
      for (int fj = 0; fj < 4; ++fj)
        acc[fi][fj] = __builtin_amdgcn_mfma_f32_16x16x32_bf16(af[fi], bf[fj],
                                                              acc[fi][fj], 0, 0, 0);
  }

  // ---------------- epilogue: masked exp sums, row-side + col-side ----------------
  int qlabv[4];
  float qvalf[4];
  float csum[4] = {0.f, 0.f, 0.f, 0.f};
  #pragma unroll
  for (int fj = 0; fj < 4; ++fj) {
    const int cl = wc * 64 + fj * 16 + cq;
    qlabv[fj] = labq_s[cl];
    qvalf[fj] = valq_s[cl] ? 1.f : 0.f;
  }
  #pragma unroll
  for (int fi = 0; fi < 4; ++fi) {
    #pragma unroll
    for (int reg = 0; reg < 4; ++reg) {
      const int rl = wr * 64 + fi * 16 + rq * 4 + reg;    // C row = (lane>>4)*4+reg
      const int rlab = labp_s[rl];
      const float rvalf = valp_s[rl] ? 1.f : 0.f;
      float rsum = 0.f;
      #pragma unroll
      for (int fj = 0; fj < 4; ++fj) {
        const float y = acc[fi][fj][reg] * SCALE_Y;
        const float negm = (qlabv[fj] != rlab) ? (qvalf[fj] * rvalf) : 0.f;
        const float term = negm * exp2f(y - M0y);
        rsum += term;
        csum[fj] += term;
      }
      rsum += __shfl_xor(rsum, 1); rsum += __shfl_xor(rsum, 2);
      rsum += __shfl_xor(rsum, 4); rsum += __shfl_xor(rsum, 8);
      if (cq == 0) atomicAdd(&rowsum_lds[rl], rsum);
    }
  }
  if (!diag) {
    #pragma unroll
    for (int fj = 0; fj < 4; ++fj) {
      float c = csum[fj];
      c += __shfl_xor(c, 16); c += __shfl_xor(c, 32);
      if (rq == 0) atomicAdd(&colsum_lds[wc * 64 + fj * 16 + cq], c);
    }
  }
  __syncthreads();
  if (t < 128) {
    atomicAdd(&rowsum_g[bl * Pp + p0 + t], rowsum_lds[t]);
    if (!diag) atomicAdd(&rowsum_g[bl * Pp + q0 + t], colsum_lds[t]);
  }
}

// ---------------- finalize ----------------
__global__ void finalize_k(const float* __restrict__ rowsum_g, const float* __restrict__ zp_g,
                           const float* __restrict__ zl_g, const int* __restrict__ negc,
                           const int* __restrict__ thing, const int* __restrict__ Kv,
                           const int* __restrict__ gatev, float* __restrict__ out) {
  const int bl = blockIdx.x, b = bl / Ll, t = threadIdx.x;
  const int Kb = Kv[b];
  const float invK = 1.f / (float)max(Kb, 1);
  float acc = 0.f;
  for (int p = t; p < Pp; p += 256) {
    if (thing[b * Pp + p] != 0) {
      const float yp = zp_g[bl * Pp + p], yl = zl_g[bl * Pp + p];
      const float rs = rowsum_g[bl * Pp + p];
      const int nc = negc[b * Pp + p];
      const float pad = fmaxf((float)(Kb - 1 - nc), 0.f);
      const float tot = exp2f(yp - M0y) + rs + ((nc > 0) ? pad * exp2f(yl - M0y) : 0.f);
      acc += LN2f * (M0y + log2f(tot) - yp) * invK;
    }
  }
  __shared__ float sb[256];
  sb[t] = acc;
  __syncthreads();
  for (int s = 128; s; s >>= 1) {
    if (t < s) sb[t] += sb[t + s];
    __syncthreads();
  }
  if (t == 0 && gatev[b]) atomicAdd(out, sb[0]);
}

}  // namespace

extern "C" void kernel_launch(void* const* d_in, const int* in_sizes, int n_in,
                              void* d_out, int out_size, void* d_ws, size_t ws_size,
                              hipStream_t stream) {
  const float* meta = (const float*)d_in[0];
  const int* thing  = (const int*)d_in[1];
  const int* label  = (const int*)d_in[2];
  float* out = (float*)d_out;

  char* ws = (char*)d_ws;
  size_t off = 0;
  unsigned short* wn = (unsigned short*)(ws + off); off += (size_t)Bb * Ll * Pp * Dd * 2; // 25.2 MB
  int* qpos  = (int*)(ws + off); off += (size_t)Bb * Ll * Pp * 4;
  int* negc  = (int*)(ws + off); off += (size_t)Bb * Pp * 4;
  int* qidx  = (int*)(ws + off); off += (size_t)Bb * Pp * 4;
  int* Kv    = (int*)(ws + off); off += 64;
  int* gatev = (int*)(ws + off); off += 64;
  float* rowsum_g = (float*)(ws + off); off += (size_t)Bb * Ll * Pp * 4;
  float* zp_g     = (float*)(ws + off); off += (size_t)Bb * Ll * Pp * 4;
  float* zl_g     = (float*)(ws + off); off += (size_t)Bb * Ll * Pp * 4;

  const int nb_prep = NB_NORM + NB_ROW + Bb + 48 + 1;  // 14345
  prep_k<<<nb_prep, 256, 0, stream>>>(meta, thing, label, wn, qpos, negc, qidx,
                                      Kv, gatev, rowsum_g, out);
  zpzl_k<<<(Bb * Ll * Pp) / 4, 256, 0, stream>>>(wn, qpos, qidx, zp_g, zl_g);
  {
    dim3 grid(36, Bb * Ll);   // 36 upper-tri tile pairs x 48 (b,l) slabs = 1728 blocks
    gemm_loss_k<<<grid, 256, 0, stream>>>(wn, thing, label, rowsum_g);
  }
  finalize_k<<<Bb * Ll, 256, 0, stream>>>(rowsum_g, zp_g, zl_g, negc, thing, Kv, gatev, out);
}

// Round 9
// 161.416 us; speedup vs baseline: 1.1263x; 1.1263x over previous
//
#include <hip/hip_runtime.h>
#include <stdint.h>

namespace {

constexpr int Bb = 8, Ll = 6, Dd = 256, Pp = 1024;
constexpr float SCALE_Y = 14.285714285714286f * 1.4426950408889634f; // (1/0.07)*log2(e)
constexpr float M0y = 21.0f;   // > max |y| = 20.61
constexpr float LN2f = 0.6931471805599453f;

typedef __attribute__((ext_vector_type(4))) float floatx4;

// upper-triangular tile pairs (pt<=qt), encoded pt*16+qt
__device__ const int PAIRS[36] = {
  0x00,0x01,0x02,0x03,0x04,0x05,0x06,0x07,
  0x11,0x12,0x13,0x14,0x15,0x16,0x17,
  0x22,0x23,0x24,0x25,0x26,0x27,
  0x33,0x34,0x35,0x36,0x37,
  0x44,0x45,0x46,0x47,
  0x55,0x56,0x57,
  0x66,0x67,
  0x77
};

// async global->LDS DMA, 16B per lane; LDS dest = wave-uniform base + lane*16
__device__ __forceinline__ void async16(const void* g, void* l) {
  __builtin_amdgcn_global_load_lds(
      (const __attribute__((address_space(1))) void*)g,
      (__attribute__((address_space(3))) void*)l, 16, 0, 0);
}

// ---------------- JAX threefry2x32 (key = (0, 42)), bit-exact ----------------
__device__ __forceinline__ uint32_t rotl32(uint32_t x, int n) {
  return (x << n) | (x >> (32 - n));
}
__device__ __forceinline__ void tf_round(uint32_t& x0, uint32_t& x1, int r) {
  x0 += x1; x1 = rotl32(x1, r); x1 ^= x0;
}
__device__ void threefry2x32(uint32_t x0, uint32_t x1, uint32_t& o0, uint32_t& o1) {
  const uint32_t k0 = 0u, k1 = 42u;
  const uint32_t k2 = k0 ^ k1 ^ 0x1BD11BDAu;
  x0 += k0; x1 += k1;
  tf_round(x0,x1,13); tf_round(x0,x1,15); tf_round(x0,x1,26); tf_round(x0,x1,6);
  x0 += k1; x1 += k2 + 1u;
  tf_round(x0,x1,17); tf_round(x0,x1,29); tf_round(x0,x1,16); tf_round(x0,x1,24);
  x0 += k2; x1 += k0 + 2u;
  tf_round(x0,x1,13); tf_round(x0,x1,15); tf_round(x0,x1,26); tf_round(x0,x1,6);
  x0 += k0; x1 += k1 + 3u;
  tf_round(x0,x1,17); tf_round(x0,x1,29); tf_round(x0,x1,16); tf_round(x0,x1,24);
  x0 += k1; x1 += k2 + 4u;
  tf_round(x0,x1,13); tf_round(x0,x1,15); tf_round(x0,x1,26); tf_round(x0,x1,6);
  x0 += k2; x1 += k0 + 5u;
  o0 = x0; o1 = x1;
}
__device__ float jax_u01(uint32_t idx) {
  const uint32_t HALF = (uint32_t)(Bb * Ll * Pp / 2); // 24576
  uint32_t o0, o1, bits;
  if (idx < HALF) { threefry2x32(idx, idx + HALF, o0, o1); bits = o0; }
  else            { threefry2x32(idx - HALF, idx, o0, o1); bits = o1; }
  return __uint_as_float((bits >> 9) | 0x3f800000u) - 1.0f;
}

// ---------------- OCP fp8 e4m3fn encode (RNE) / decode ----------------
// inputs are |x| <= 1 (unit-normalized components), so no overflow/NaN paths.
__device__ __forceinline__ uint32_t fp8e4m3_rne(float x) {
  uint32_t u = __float_as_uint(x);
  const uint32_t s = (u >> 24) & 0x80u;
  u &= 0x7FFFFFFFu;
  uint32_t code;
  if (u < 0x3C800000u) {                       // |x| < 2^-6: subnormal (step 2^-9)
    code = (uint32_t)__float2int_rn(__uint_as_float(u) * 512.0f);  // 0..8 (8 rolls to normal min)
  } else {
    const uint32_t r = (u + 0x7FFFFu + ((u >> 20) & 1u)) >> 20;    // e8[..3]|m[2:0], RNE
    code = r - (120u << 3);                     // rebias 127->7
  }
  return s | code;
}
__device__ __forceinline__ float fp8e4m3_tof(uint32_t c) {
  const uint32_t e = (c >> 3) & 15u, m = c & 7u;
  float mag;
  if (e) mag = __uint_as_float(((e + 120u) << 23) | (m << 20));
  else   mag = (float)m * 0.001953125f;        // m * 2^-9
  return (c & 0x80u) ? -mag : mag;
}

// ---------------- fused prep kernel (block-range dispatch) ----------------
constexpr int NB_NORM = Bb * Pp * Ll / 4;  // 12288
constexpr int NB_ROW  = Bb * Pp / 4;       // 2048

__global__ void prep_k(const float* __restrict__ meta, const int* __restrict__ thing,
                       const int* __restrict__ label, uint8_t* __restrict__ wn,
                       int* __restrict__ qpos, int* __restrict__ negc,
                       int* __restrict__ qidx, int* __restrict__ Kv,
                       int* __restrict__ gatev, float* __restrict__ rowsum_g,
                       float* __restrict__ out) {
  __shared__ int sK[256], sG[256];
  const int bid = blockIdx.x, t = threadIdx.x;

  if (bid < NB_NORM) {
    // ---- normalize + fp8 e4m3 convert ----
    const int wid = (bid * 256 + t) >> 6;   // (b*P+p)*L+l
    const int lane = t & 63;
    const float4 v = *(const float4*)(meta + (size_t)wid * Dd + lane * 4);
    float ss = v.x * v.x + v.y * v.y + v.z * v.z + v.w * v.w;
    #pragma unroll
    for (int m = 32; m; m >>= 1) ss += __shfl_xor(ss, m, 64);
    const float inv = 1.0f / fmaxf(sqrtf(ss), 1e-12f);
    const int bp = wid / Ll, l = wid - bp * Ll;
    const int b = bp >> 10, p = bp & (Pp - 1);
    uint8_t* dst = wn + ((size_t)(b * Ll + l) * Pp + p) * Dd + lane * 4;
    const uint32_t packed = fp8e4m3_rne(v.x * inv)
                          | (fp8e4m3_rne(v.y * inv) << 8)
                          | (fp8e4m3_rne(v.z * inv) << 16)
                          | (fp8e4m3_rne(v.w * inv) << 24);
    *(uint32_t*)dst = packed;
    return;
  }
  if (bid < NB_NORM + NB_ROW) {
    // ---- row stats: one wave per (b,p) ----
    const int wid = (bid - NB_NORM) * 4 + (t >> 6);
    const int lane = t & 63;
    const int b = wid >> 10, p = wid & (Pp - 1);
    const int* lab = label + b * Pp;
    const int* th  = thing + b * Pp;
    const int myLab = lab[p];
    const bool myValid = (th[p] != 0);

    uint32_t posbits = 0;
    int cnt[16];
    int pc = 0, nc = 0, last = -1;
    #pragma unroll
    for (int c = 0; c < 16; ++c) {
      const int q = c * 64 + lane;
      const int lq = lab[q];
      const bool vq = (th[q] != 0);
      const bool same = (lq == myLab);
      const bool pos = myValid && vq && same && (q != p);
      const bool neg = myValid && vq && !same;
      uint64_t bp2 = __ballot(pos);
      uint64_t bn = __ballot(neg);
      if (pos) posbits |= (1u << c);
      cnt[c] = __popcll(bp2);
      pc += cnt[c];
      nc += __popcll(bn);
      if (bn) last = c * 64 + 63 - __clzll(bn);
    }
    int qsel[Ll];
    #pragma unroll
    for (int l = 0; l < Ll; ++l) qsel[l] = p;
    if (pc > 0) {
      for (int l = 0; l < Ll; ++l) {
        const float u = jax_u01((uint32_t)((b * Ll + l) * Pp + p));
        int r = (int)floorf(u * (float)pc);
        r = min(r, pc - 1);
        int base = 0;
        for (int c = 0; c < 16; ++c) {
          if (r < base + cnt[c]) {
            const bool mine = (posbits >> c) & 1u;
            uint64_t bm = __ballot(mine);
            uint64_t ltmask = (lane == 0) ? 0ull : (~0ull >> (64 - lane));
            int myrank = __popcll(bm & ltmask);
            bool hit = mine && (base + myrank == r);
            uint64_t hb = __ballot(hit);
            qsel[l] = c * 64 + (int)__builtin_ctzll(hb);
            break;
          }
          base += cnt[c];
        }
      }
    }
    if (lane == 0) {
      negc[wid] = nc;
      qidx[wid] = (last < 0) ? 0 : last;
      #pragma unroll
      for (int l = 0; l < Ll; ++l) qpos[(b * Ll + l) * Pp + p] = qsel[l];
    }
    return;
  }
  if (bid < NB_NORM + NB_ROW + Bb) {
    // ---- batch stats ----
    const int b = bid - (NB_NORM + NB_ROW);
    int k = 0;
    for (int p = t; p < Pp; p += 256) k += (thing[b * Pp + p] != 0);
    int g = 0;
    if (t < 128) {
      int any = 0;
      for (int tt = 0; tt < 8; ++tt) any |= (thing[(b * 128 + t) * 8 + tt] != 0);
      g = any;
    }
    sK[t] = k; sG[t] = g;
    __syncthreads();
    for (int s = 128; s; s >>= 1) {
      if (t < s) { sK[t] += sK[t + s]; sG[t] += sG[t + s]; }
      __syncthreads();
    }
    if (t == 0) { Kv[b] = sK[0]; gatev[b] = (sG[0] >= 2) ? 1 : 0; }
    return;
  }
  if (bid < NB_NORM + NB_ROW + Bb + 48) {
    // ---- zero rowsum_g ----
    const int idx = (bid - (NB_NORM + NB_ROW + Bb)) * 256 + t;
    *(float4*)(rowsum_g + idx * 4) = (float4){0.f, 0.f, 0.f, 0.f};
    return;
  }
  if (t == 0) out[0] = 0.f;
}

// ---------------- zp/zl via direct fp8 dots (one wave per (bl,p)) ----------------
__global__ void zpzl_k(const uint8_t* __restrict__ wn,
                       const int* __restrict__ qpos, const int* __restrict__ qidx,
                       float* __restrict__ zp_g, float* __restrict__ zl_g) {
  const int wid = blockIdx.x * 4 + (threadIdx.x >> 6);  // bl*1024+p
  const int lane = threadIdx.x & 63;
  const int bl = wid >> 10, p = wid & (Pp - 1);
  const int b = bl / Ll;
  const int qp = qpos[bl * Pp + p];
  const int qi = qidx[b * Pp + p];
  const uint8_t* W = wn + (size_t)bl * Pp * Dd;
  const uint32_t a4 = *(const uint32_t*)(W + (size_t)p  * Dd + lane * 4);
  const uint32_t b4 = *(const uint32_t*)(W + (size_t)qp * Dd + lane * 4);
  const uint32_t c4 = *(const uint32_t*)(W + (size_t)qi * Dd + lane * 4);
  float sp = 0.f, sl = 0.f;
  #pragma unroll
  for (int i = 0; i < 4; ++i) {
    const float a = fp8e4m3_tof((a4 >> (8 * i)) & 0xFF);
    sp += a * fp8e4m3_tof((b4 >> (8 * i)) & 0xFF);
    sl += a * fp8e4m3_tof((c4 >> (8 * i)) & 0xFF);
  }
  #pragma unroll
  for (int m = 32; m; m >>= 1) {
    sp += __shfl_xor(sp, m, 64);
    sl += __shfl_xor(sl, m, 64);
  }
  if (lane == 0) {
    zp_g[bl * Pp + p] = sp * SCALE_Y;
    zl_g[bl * Pp + p] = sl * SCALE_Y;
  }
}

// ---------------- fp8 MFMA Gram, upper-tri pairs, BK=128, 2 barrier rounds ----------------
// r7 structure with 1B operands: same 32 KB LDS budget holds K=128 per round ->
// 2 rounds instead of 4 (halves barrier drains), DMA insts halve, LDS read bytes
// halve. MFMA count unchanged (fp8 16x16x32 = bf16 rate). Same XOR-16B-chunk
// swizzle; fragments are 8B ds_read at row*128 + ((sub*2+(rq>>1))^(row&7))*16 + (rq&1)*8.
// No min-waves launch_bounds (r4: reg cap spilled acc to scratch).
__global__ __launch_bounds__(256)
void gemm_loss_k(const uint8_t* __restrict__ wn,
                 const int* __restrict__ thing, const int* __restrict__ label,
                 float* __restrict__ rowsum_g) {
  __shared__ __align__(16) uint8_t As[128 * 128];  // 16 KB: physical chunk c at byte c*16
  __shared__ __align__(16) uint8_t Bs[128 * 128];
  __shared__ int labp_s[128], valp_s[128], labq_s[128], valq_s[128];
  __shared__ float rowsum_lds[128], colsum_lds[128];

  const int t = threadIdx.x;
  const int bl = blockIdx.y;
  const int b = bl / Ll;
  const int pair = PAIRS[blockIdx.x];
  const int pt = pair >> 4, qt = pair & 15;
  const bool diag = (pt == qt);
  const int p0 = pt * 128, q0 = qt * 128;

  if (t < 128) {
    labp_s[t] = label[b * Pp + p0 + t];
    valp_s[t] = thing[b * Pp + p0 + t];
    labq_s[t] = label[b * Pp + q0 + t];
    valq_s[t] = thing[b * Pp + q0 + t];
    rowsum_lds[t] = 0.f;
    colsum_lds[t] = 0.f;
  }

  const uint8_t* Wbl = wn + (size_t)bl * Pp * Dd;
  const int lane = t & 63;
  const int w = t >> 6, wr = w >> 1, wc = w & 1;
  const int cq = lane & 15, rq = lane >> 4;
  const int wbase16 = (t & ~63) * 16;  // wave-uniform lds byte base per 64-lane group

  floatx4 acc[4][4];
  #pragma unroll
  for (int i = 0; i < 4; ++i)
    #pragma unroll
    for (int j = 0; j < 4; ++j) acc[i][j] = (floatx4){0.f, 0.f, 0.f, 0.f};

  const uint8_t* Bbase = diag ? As : Bs;

  for (int k0 = 0; k0 < Dd; k0 += 128) {   // bytes == elements; 2 rounds
    __syncthreads();   // LDS safe to overwrite (also orders the t<128 preload, 1st iter)
    #pragma unroll
    for (int it = 0; it < 4; ++it) {
      const int c = it * 256 + t;            // 16B chunk id: row = c>>3, physical sp = c&7
      const int row = c >> 3, sp = c & 7;
      const int sl = sp ^ (row & 7);         // XOR swizzle: logical k-slot stored here
      async16(Wbl + (size_t)(p0 + row) * Dd + k0 + sl * 16, As + it * 4096 + wbase16);
      if (!diag)
        async16(Wbl + (size_t)(q0 + row) * Dd + k0 + sl * 16, Bs + it * 4096 + wbase16);
    }
    __syncthreads();   // drains vmcnt -> tiles visible
    #pragma unroll
    for (int sub = 0; sub < 4; ++sub) {      // k = k0 + sub*32 .. +31
      const int Lw = sub * 2 + (rq >> 1);    // logical 16B chunk within row
      const int off8 = (rq & 1) * 8;
      long long af[4], bf[4];
      #pragma unroll
      for (int fi = 0; fi < 4; ++fi) {
        const int row = wr * 64 + fi * 16 + cq;           // A row m = lane&15
        af[fi] = *(const long long*)(As + row * 128 + (Lw ^ (row & 7)) * 16 + off8);
      }
      #pragma unroll
      for (int fj = 0; fj < 4; ++fj) {
        const int row = wc * 64 + fj * 16 + cq;           // B row n = lane&15
        bf[fj] = *(const long long*)(Bbase + row * 128 + (Lw ^ (row & 7)) * 16 + off8);
      }
      #pragma unroll
      for (int fi = 0; fi < 4; ++fi)
        #pragma unroll
        for (int fj = 0; fj < 4; ++fj)
          acc[fi][fj] = __builtin_amdgcn_mfma_f32_16x16x32_fp8_fp8(af[fi], bf[fj],
                                                                   acc[fi][fj], 0, 0, 0);
    }
  }

  // ---------------- epilogue: masked exp sums, row-side + col-side ----------------
  int qlabv[4];
  float qvalf[4];
  float csum[4] = {0.f, 0.f, 0.f, 0.f};
  #pragma unroll
  for (int fj = 0; fj < 4; ++fj) {
    const int cl = wc * 64 + fj * 16 + cq;
    qlabv[fj] = labq_s[cl];
    qvalf[fj] = valq_s[cl] ? 1.f : 0.f;
  }
  #pragma unroll
  for (int fi = 0; fi < 4; ++fi) {
    #pragma unroll
    for (int reg = 0; reg < 4; ++reg) {
      const int rl = wr * 64 + fi * 16 + rq * 4 + reg;    // C row = (lane>>4)*4+reg
      const int rlab = labp_s[rl];
      const float rvalf = valp_s[rl] ? 1.f : 0.f;
      float rsum = 0.f;
      #pragma unroll
      for (int fj = 0; fj < 4; ++fj) {
        const float y = acc[fi][fj][reg] * SCALE_Y;
        const float negm = (qlabv[fj] != rlab) ? (qvalf[fj] * rvalf) : 0.f;
        const float term = negm * exp2f(y - M0y);
        rsum += term;
        csum[fj] += term;
      }
      rsum += __shfl_xor(rsum, 1); rsum += __shfl_xor(rsum, 2);
      rsum += __shfl_xor(rsum, 4); rsum += __shfl_xor(rsum, 8);
      if (cq == 0) atomicAdd(&rowsum_lds[rl], rsum);
    }
  }
  if (!diag) {
    #pragma unroll
    for (int fj = 0; fj < 4; ++fj) {
      float c = csum[fj];
      c += __shfl_xor(c, 16); c += __shfl_xor(c, 32);
      if (rq == 0) atomicAdd(&colsum_lds[wc * 64 + fj * 16 + cq], c);
    }
  }
  __syncthreads();
  if (t < 128) {
    atomicAdd(&rowsum_g[bl * Pp + p0 + t], rowsum_lds[t]);
    if (!diag) atomicAdd(&rowsum_g[bl * Pp + q0 + t], colsum_lds[t]);
  }
}

// ---------------- finalize ----------------
__global__ void finalize_k(const float* __restrict__ rowsum_g, const float* __restrict__ zp_g,
                           const float* __restrict__ zl_g, const int* __restrict__ negc,
                           const int* __restrict__ thing, const int* __restrict__ Kv,
                           const int* __restrict__ gatev, float* __restrict__ out) {
  const int bl = blockIdx.x, b = bl / Ll, t = threadIdx.x;
  const int Kb = Kv[b];
  const float invK = 1.f / (float)max(Kb, 1);
  float acc = 0.f;
  for (int p = t; p < Pp; p += 256) {
    if (thing[b * Pp + p] != 0) {
      const float yp = zp_g[bl * Pp + p], yl = zl_g[bl * Pp + p];
      const float rs = rowsum_g[bl * Pp + p];
      const int nc = negc[b * Pp + p];
      const float pad = fmaxf((float)(Kb - 1 - nc), 0.f);
      const float tot = exp2f(yp - M0y) + rs + ((nc > 0) ? pad * exp2f(yl - M0y) : 0.f);
      acc += LN2f * (M0y + log2f(tot) - yp) * invK;
    }
  }
  __shared__ float sb[256];
  sb[t] = acc;
  __syncthreads();
  for (int s = 128; s; s >>= 1) {
    if (t < s) sb[t] += sb[t + s];
    __syncthreads();
  }
  if (t == 0 && gatev[b]) atomicAdd(out, sb[0]);
}

}  // namespace

extern "C" void kernel_launch(void* const* d_in, const int* in_sizes, int n_in,
                              void* d_out, int out_size, void* d_ws, size_t ws_size,
                              hipStream_t stream) {
  const float* meta = (const float*)d_in[0];
  const int* thing  = (const int*)d_in[1];
  const int* label  = (const int*)d_in[2];
  float* out = (float*)d_out;

  char* ws = (char*)d_ws;
  size_t off = 0;
  uint8_t* wn = (uint8_t*)(ws + off); off += (size_t)Bb * Ll * Pp * Dd;  // 12.6 MB fp8
  int* qpos  = (int*)(ws + off); off += (size_t)Bb * Ll * Pp * 4;
  int* negc  = (int*)(ws + off); off += (size_t)Bb * Pp * 4;
  int* qidx  = (int*)(ws + off); off += (size_t)Bb * Pp * 4;
  int* Kv    = (int*)(ws + off); off += 64;
  int* gatev = (int*)(ws + off); off += 64;
  float* rowsum_g = (float*)(ws + off); off += (size_t)Bb * Ll * Pp * 4;
  float* zp_g     = (float*)(ws + off); off += (size_t)Bb * Ll * Pp * 4;
  float* zl_g     = (float*)(ws + off); off += (size_t)Bb * Ll * Pp * 4;

  const int nb_prep = NB_NORM + NB_ROW + Bb + 48 + 1;  // 14345
  prep_k<<<nb_prep, 256, 0, stream>>>(meta, thing, label, wn, qpos, negc, qidx,
                                      Kv, gatev, rowsum_g, out);
  zpzl_k<<<(Bb * Ll * Pp) / 4, 256, 0, stream>>>(wn, qpos, qidx, zp_g, zl_g);
  {
    dim3 grid(36, Bb * Ll);   // 36 upper-tri tile pairs x 48 (b,l) slabs = 1728 blocks
    gemm_loss_k<<<grid, 256, 0, stream>>>(wn, thing, label, rowsum_g);
  }
  finalize_k<<<Bb * Ll, 256, 0, stream>>>(rowsum_g, zp_g, zl_g, negc, thing, Kv, gatev, out);
}

// Round 10
// 155.843 us; speedup vs baseline: 1.1665x; 1.0358x over previous
//
#include <hip/hip_runtime.h>
#include <stdint.h>

namespace {

constexpr int Bb = 8, Ll = 6, Dd = 256, Pp = 1024;
constexpr float SCALE_Y = 14.285714285714286f * 1.4426950408889634f; // (1/0.07)*log2(e)
constexpr float M0y = 21.0f;   // > max |y| = 20.61
constexpr float LN2f = 0.6931471805599453f;

typedef __attribute__((ext_vector_type(4))) float floatx4;

// upper-triangular tile pairs (pt<=qt), encoded pt*16+qt
__device__ const int PAIRS[36] = {
  0x00,0x01,0x02,0x03,0x04,0x05,0x06,0x07,
  0x11,0x12,0x13,0x14,0x15,0x16,0x17,
  0x22,0x23,0x24,0x25,0x26,0x27,
  0x33,0x34,0x35,0x36,0x37,
  0x44,0x45,0x46,0x47,
  0x55,0x56,0x57,
  0x66,0x67,
  0x77
};

// async global->LDS DMA, 16B per lane; LDS dest = wave-uniform base + lane*16
__device__ __forceinline__ void async16(const void* g, void* l) {
  __builtin_amdgcn_global_load_lds(
      (const __attribute__((address_space(1))) void*)g,
      (__attribute__((address_space(3))) void*)l, 16, 0, 0);
}

// ---------------- JAX threefry2x32 (key = (0, 42)), bit-exact ----------------
__device__ __forceinline__ uint32_t rotl32(uint32_t x, int n) {
  return (x << n) | (x >> (32 - n));
}
__device__ __forceinline__ void tf_round(uint32_t& x0, uint32_t& x1, int r) {
  x0 += x1; x1 = rotl32(x1, r); x1 ^= x0;
}
__device__ void threefry2x32(uint32_t x0, uint32_t x1, uint32_t& o0, uint32_t& o1) {
  const uint32_t k0 = 0u, k1 = 42u;
  const uint32_t k2 = k0 ^ k1 ^ 0x1BD11BDAu;
  x0 += k0; x1 += k1;
  tf_round(x0,x1,13); tf_round(x0,x1,15); tf_round(x0,x1,26); tf_round(x0,x1,6);
  x0 += k1; x1 += k2 + 1u;
  tf_round(x0,x1,17); tf_round(x0,x1,29); tf_round(x0,x1,16); tf_round(x0,x1,24);
  x0 += k2; x1 += k0 + 2u;
  tf_round(x0,x1,13); tf_round(x0,x1,15); tf_round(x0,x1,26); tf_round(x0,x1,6);
  x0 += k0; x1 += k1 + 3u;
  tf_round(x0,x1,17); tf_round(x0,x1,29); tf_round(x0,x1,16); tf_round(x0,x1,24);
  x0 += k1; x1 += k2 + 4u;
  tf_round(x0,x1,13); tf_round(x0,x1,15); tf_round(x0,x1,26); tf_round(x0,x1,6);
  x0 += k2; x1 += k0 + 5u;
  o0 = x0; o1 = x1;
}
__device__ float jax_u01(uint32_t idx) {
  const uint32_t HALF = (uint32_t)(Bb * Ll * Pp / 2); // 24576
  uint32_t o0, o1, bits;
  if (idx < HALF) { threefry2x32(idx, idx + HALF, o0, o1); bits = o0; }
  else            { threefry2x32(idx - HALF, idx, o0, o1); bits = o1; }
  return __uint_as_float((bits >> 9) | 0x3f800000u) - 1.0f;
}

// ---------------- OCP fp8 e4m3fn encode (RNE) / decode ----------------
// inputs are |x| <= 1 (unit-normalized components), so no overflow/NaN paths.
__device__ __forceinline__ uint32_t fp8e4m3_rne(float x) {
  uint32_t u = __float_as_uint(x);
  const uint32_t s = (u >> 24) & 0x80u;
  u &= 0x7FFFFFFFu;
  uint32_t code;
  if (u < 0x3C800000u) {                       // |x| < 2^-6: subnormal (step 2^-9)
    code = (uint32_t)__float2int_rn(__uint_as_float(u) * 512.0f);  // 0..8 (8 rolls to normal min)
  } else {
    const uint32_t r = (u + 0x7FFFFu + ((u >> 20) & 1u)) >> 20;    // e8[..3]|m[2:0], RNE
    code = r - (120u << 3);                     // rebias 127->7
  }
  return s | code;
}
__device__ __forceinline__ float fp8e4m3_tof(uint32_t c) {
  const uint32_t e = (c >> 3) & 15u, m = c & 7u;
  float mag;
  if (e) mag = __uint_as_float(((e + 120u) << 23) | (m << 20));
  else   mag = (float)m * 0.001953125f;        // m * 2^-9
  return (c & 0x80u) ? -mag : mag;
}

// ---------------- fused prep kernel (block-range dispatch) ----------------
constexpr int NB_NORM = Bb * Pp * Ll / 4;  // 12288
constexpr int NB_ROW  = Bb * Pp / 4;       // 2048

__global__ void prep_k(const float* __restrict__ meta, const int* __restrict__ thing,
                       const int* __restrict__ label, uint8_t* __restrict__ wn,
                       int* __restrict__ qpos, int* __restrict__ negc,
                       int* __restrict__ qidx, int* __restrict__ Kv,
                       int* __restrict__ gatev, float* __restrict__ rowsum_g,
                       float* __restrict__ out) {
  __shared__ int sK[256], sG[256];
  const int bid = blockIdx.x, t = threadIdx.x;

  if (bid < NB_NORM) {
    // ---- normalize + fp8 e4m3 convert ----
    const int wid = (bid * 256 + t) >> 6;   // (b*P+p)*L+l
    const int lane = t & 63;
    const float4 v = *(const float4*)(meta + (size_t)wid * Dd + lane * 4);
    float ss = v.x * v.x + v.y * v.y + v.z * v.z + v.w * v.w;
    #pragma unroll
    for (int m = 32; m; m >>= 1) ss += __shfl_xor(ss, m, 64);
    const float inv = 1.0f / fmaxf(sqrtf(ss), 1e-12f);
    const int bp = wid / Ll, l = wid - bp * Ll;
    const int b = bp >> 10, p = bp & (Pp - 1);
    uint8_t* dst = wn + ((size_t)(b * Ll + l) * Pp + p) * Dd + lane * 4;
    const uint32_t packed = fp8e4m3_rne(v.x * inv)
                          | (fp8e4m3_rne(v.y * inv) << 8)
                          | (fp8e4m3_rne(v.z * inv) << 16)
                          | (fp8e4m3_rne(v.w * inv) << 24);
    *(uint32_t*)dst = packed;
    return;
  }
  if (bid < NB_NORM + NB_ROW) {
    // ---- row stats: one wave per (b,p) ----
    const int wid = (bid - NB_NORM) * 4 + (t >> 6);
    const int lane = t & 63;
    const int b = wid >> 10, p = wid & (Pp - 1);
    const int* lab = label + b * Pp;
    const int* th  = thing + b * Pp;
    const int myLab = lab[p];
    const bool myValid = (th[p] != 0);

    uint32_t posbits = 0;
    int cnt[16];
    int pc = 0, nc = 0, last = -1;
    #pragma unroll
    for (int c = 0; c < 16; ++c) {
      const int q = c * 64 + lane;
      const int lq = lab[q];
      const bool vq = (th[q] != 0);
      const bool same = (lq == myLab);
      const bool pos = myValid && vq && same && (q != p);
      const bool neg = myValid && vq && !same;
      uint64_t bp2 = __ballot(pos);
      uint64_t bn = __ballot(neg);
      if (pos) posbits |= (1u << c);
      cnt[c] = __popcll(bp2);
      pc += cnt[c];
      nc += __popcll(bn);
      if (bn) last = c * 64 + 63 - __clzll(bn);
    }
    int qsel[Ll];
    #pragma unroll
    for (int l = 0; l < Ll; ++l) qsel[l] = p;
    if (pc > 0) {
      for (int l = 0; l < Ll; ++l) {
        const float u = jax_u01((uint32_t)((b * Ll + l) * Pp + p));
        int r = (int)floorf(u * (float)pc);
        r = min(r, pc - 1);
        int base = 0;
        for (int c = 0; c < 16; ++c) {
          if (r < base + cnt[c]) {
            const bool mine = (posbits >> c) & 1u;
            uint64_t bm = __ballot(mine);
            uint64_t ltmask = (lane == 0) ? 0ull : (~0ull >> (64 - lane));
            int myrank = __popcll(bm & ltmask);
            bool hit = mine && (base + myrank == r);
            uint64_t hb = __ballot(hit);
            qsel[l] = c * 64 + (int)__builtin_ctzll(hb);
            break;
          }
          base += cnt[c];
        }
      }
    }
    if (lane == 0) {
      negc[wid] = nc;
      qidx[wid] = (last < 0) ? 0 : last;
      #pragma unroll
      for (int l = 0; l < Ll; ++l) qpos[(b * Ll + l) * Pp + p] = qsel[l];
    }
    return;
  }
  if (bid < NB_NORM + NB_ROW + Bb) {
    // ---- batch stats ----
    const int b = bid - (NB_NORM + NB_ROW);
    int k = 0;
    for (int p = t; p < Pp; p += 256) k += (thing[b * Pp + p] != 0);
    int g = 0;
    if (t < 128) {
      int any = 0;
      for (int tt = 0; tt < 8; ++tt) any |= (thing[(b * 128 + t) * 8 + tt] != 0);
      g = any;
    }
    sK[t] = k; sG[t] = g;
    __syncthreads();
    for (int s = 128; s; s >>= 1) {
      if (t < s) { sK[t] += sK[t + s]; sG[t] += sG[t + s]; }
      __syncthreads();
    }
    if (t == 0) { Kv[b] = sK[0]; gatev[b] = (sG[0] >= 2) ? 1 : 0; }
    return;
  }
  if (bid < NB_NORM + NB_ROW + Bb + 48) {
    // ---- zero rowsum_g ----
    const int idx = (bid - (NB_NORM + NB_ROW + Bb)) * 256 + t;
    *(float4*)(rowsum_g + idx * 4) = (float4){0.f, 0.f, 0.f, 0.f};
    return;
  }
  if (t == 0) out[0] = 0.f;
}

// ---------------- zp/zl via direct fp8 dots (one wave per (bl,p)) ----------------
__global__ void zpzl_k(const uint8_t* __restrict__ wn,
                       const int* __restrict__ qpos, const int* __restrict__ qidx,
                       float* __restrict__ zp_g, float* __restrict__ zl_g) {
  const int wid = blockIdx.x * 4 + (threadIdx.x >> 6);  // bl*1024+p
  const int lane = threadIdx.x & 63;
  const int bl = wid >> 10, p = wid & (Pp - 1);
  const int b = bl / Ll;
  const int qp = qpos[bl * Pp + p];
  const int qi = qidx[b * Pp + p];
  const uint8_t* W = wn + (size_t)bl * Pp * Dd;
  const uint32_t a4 = *(const uint32_t*)(W + (size_t)p  * Dd + lane * 4);
  const uint32_t b4 = *(const uint32_t*)(W + (size_t)qp * Dd + lane * 4);
  const uint32_t c4 = *(const uint32_t*)(W + (size_t)qi * Dd + lane * 4);
  float sp = 0.f, sl = 0.f;
  #pragma unroll
  for (int i = 0; i < 4; ++i) {
    const float a = fp8e4m3_tof((a4 >> (8 * i)) & 0xFF);
    sp += a * fp8e4m3_tof((b4 >> (8 * i)) & 0xFF);
    sl += a * fp8e4m3_tof((c4 >> (8 * i)) & 0xFF);
  }
  #pragma unroll
  for (int m = 32; m; m >>= 1) {
    sp += __shfl_xor(sp, m, 64);
    sl += __shfl_xor(sl, m, 64);
  }
  if (lane == 0) {
    zp_g[bl * Pp + p] = sp * SCALE_Y;
    zl_g[bl * Pp + p] = sl * SCALE_Y;
  }
}

// ---------------- fp8 MFMA Gram, upper-tri pairs, BK=128, XCD-local slabs ----------------
// 1-D grid of 1728; decode keeps all 36 tiles of a (b,l) slab on ONE XCD
// (assuming round-robin workgroup->XCD dispatch): xcd = bid&7, bl = xcd+8*(chunk%6),
// pair = chunk/6. Each 256 KB slab then lives in a single XCD L2 -> barrier drains
// wait on ~200-cyc L2 hits instead of ~900-cyc HBM misses. Speed-only heuristic.
__global__ __launch_bounds__(256)
void gemm_loss_k(const uint8_t* __restrict__ wn,
                 const int* __restrict__ thing, const int* __restrict__ label,
                 float* __restrict__ rowsum_g) {
  __shared__ __align__(16) uint8_t As[128 * 128];  // 16 KB: physical chunk c at byte c*16
  __shared__ __align__(16) uint8_t Bs[128 * 128];
  __shared__ int labp_s[128], valp_s[128], labq_s[128], valq_s[128];
  __shared__ float rowsum_lds[128], colsum_lds[128];

  const int t = threadIdx.x;
  const int bid = blockIdx.x;
  const int xcd = bid & 7;
  const int chunk = bid >> 3;          // 0..215
  const int bl = xcd + 8 * (chunk % 6);
  const int b = bl / Ll;
  const int pair = PAIRS[chunk / 6];
  const int pt = pair >> 4, qt = pair & 15;
  const bool diag = (pt == qt);
  const int p0 = pt * 128, q0 = qt * 128;

  if (t < 128) {
    labp_s[t] = label[b * Pp + p0 + t];
    valp_s[t] = thing[b * Pp + p0 + t];
    labq_s[t] = label[b * Pp + q0 + t];
    valq_s[t] = thing[b * Pp + q0 + t];
    rowsum_lds[t] = 0.f;
    colsum_lds[t] = 0.f;
  }

  const uint8_t* Wbl = wn + (size_t)bl * Pp * Dd;
  const int lane = t & 63;
  const int w = t >> 6, wr = w >> 1, wc = w & 1;
  const int cq = lane & 15, rq = lane >> 4;
  const int wbase16 = (t & ~63) * 16;  // wave-uniform lds byte base per 64-lane group

  floatx4 acc[4][4];
  #pragma unroll
  for (int i = 0; i < 4; ++i)
    #pragma unroll
    for (int j = 0; j < 4; ++j) acc[i][j] = (floatx4){0.f, 0.f, 0.f, 0.f};

  const uint8_t* Bbase = diag ? As : Bs;

  for (int k0 = 0; k0 < Dd; k0 += 128) {   // bytes == elements; 2 rounds
    __syncthreads();   // LDS safe to overwrite (also orders the t<128 preload, 1st iter)
    #pragma unroll
    for (int it = 0; it < 4; ++it) {
      const int c = it * 256 + t;            // 16B chunk id: row = c>>3, physical sp = c&7
      const int row = c >> 3, sp = c & 7;
      const int sl = sp ^ (row & 7);         // XOR swizzle: logical k-slot stored here
      async16(Wbl + (size_t)(p0 + row) * Dd + k0 + sl * 16, As + it * 4096 + wbase16);
      if (!diag)
        async16(Wbl + (size_t)(q0 + row) * Dd + k0 + sl * 16, Bs + it * 4096 + wbase16);
    }
    __syncthreads();   // drains vmcnt -> tiles visible
    #pragma unroll
    for (int sub = 0; sub < 4; ++sub) {      // k = k0 + sub*32 .. +31
      const int Lw = sub * 2 + (rq >> 1);    // logical 16B chunk within row
      const int off8 = (rq & 1) * 8;
      long long af[4], bf[4];
      #pragma unroll
      for (int fi = 0; fi < 4; ++fi) {
        const int row = wr * 64 + fi * 16 + cq;           // A row m = lane&15
        af[fi] = *(const long long*)(As + row * 128 + (Lw ^ (row & 7)) * 16 + off8);
      }
      #pragma unroll
      for (int fj = 0; fj < 4; ++fj) {
        const int row = wc * 64 + fj * 16 + cq;           // B row n = lane&15
        bf[fj] = *(const long long*)(Bbase + row * 128 + (Lw ^ (row & 7)) * 16 + off8);
      }
      #pragma unroll
      for (int fi = 0; fi < 4; ++fi)
        #pragma unroll
        for (int fj = 0; fj < 4; ++fj)
          acc[fi][fj] = __builtin_amdgcn_mfma_f32_16x16x32_fp8_fp8(af[fi], bf[fj],
                                                                   acc[fi][fj], 0, 0, 0);
    }
  }

  // ---------------- epilogue: masked exp sums, row-side + col-side ----------------
  int qlabv[4];
  float qvalf[4];
  float csum[4] = {0.f, 0.f, 0.f, 0.f};
  #pragma unroll
  for (int fj = 0; fj < 4; ++fj) {
    const int cl = wc * 64 + fj * 16 + cq;
    qlabv[fj] = labq_s[cl];
    qvalf[fj] = valq_s[cl] ? 1.f : 0.f;
  }
  #pragma unroll
  for (int fi = 0; fi < 4; ++fi) {
    #pragma unroll
    for (int reg = 0; reg < 4; ++reg) {
      const int rl = wr * 64 + fi * 16 + rq * 4 + reg;    // C row = (lane>>4)*4+reg
      const int rlab = labp_s[rl];
      const float rvalf = valp_s[rl] ? 1.f : 0.f;
      float rsum = 0.f;
      #pragma unroll
      for (int fj = 0; fj < 4; ++fj) {
        const float y = acc[fi][fj][reg] * SCALE_Y;
        const float negm = (qlabv[fj] != rlab) ? (qvalf[fj] * rvalf) : 0.f;
        const float term = negm * exp2f(y - M0y);
        rsum += term;
        csum[fj] += term;
      }
      rsum += __shfl_xor(rsum, 1); rsum += __shfl_xor(rsum, 2);
      rsum += __shfl_xor(rsum, 4); rsum += __shfl_xor(rsum, 8);
      if (cq == 0) atomicAdd(&rowsum_lds[rl], rsum);
    }
  }
  if (!diag) {
    #pragma unroll
    for (int fj = 0; fj < 4; ++fj) {
      float c = csum[fj];
      c += __shfl_xor(c, 16); c += __shfl_xor(c, 32);
      if (rq == 0) atomicAdd(&colsum_lds[wc * 64 + fj * 16 + cq], c);
    }
  }
  __syncthreads();
  if (t < 128) {
    atomicAdd(&rowsum_g[bl * Pp + p0 + t], rowsum_lds[t]);
    if (!diag) atomicAdd(&rowsum_g[bl * Pp + q0 + t], colsum_lds[t]);
  }
}

// ---------------- finalize ----------------
__global__ void finalize_k(const float* __restrict__ rowsum_g, const float* __restrict__ zp_g,
                           const float* __restrict__ zl_g, const int* __restrict__ negc,
                           const int* __restrict__ thing, const int* __restrict__ Kv,
                           const int* __restrict__ gatev, float* __restrict__ out) {
  const int bl = blockIdx.x, b = bl / Ll, t = threadIdx.x;
  const int Kb = Kv[b];
  const float invK = 1.f / (float)max(Kb, 1);
  float acc = 0.f;
  for (int p = t; p < Pp; p += 256) {
    if (thing[b * Pp + p] != 0) {
      const float yp = zp_g[bl * Pp + p], yl = zl_g[bl * Pp + p];
      const float rs = rowsum_g[bl * Pp + p];
      const int nc = negc[b * Pp + p];
      const float pad = fmaxf((float)(Kb - 1 - nc), 0.f);
      const float tot = exp2f(yp - M0y) + rs + ((nc > 0) ? pad * exp2f(yl - M0y) : 0.f);
      acc += LN2f * (M0y + log2f(tot) - yp) * invK;
    }
  }
  __shared__ float sb[256];
  sb[t] = acc;
  __syncthreads();
  for (int s = 128; s; s >>= 1) {
    if (t < s) sb[t] += sb[t + s];
    __syncthreads();
  }
  if (t == 0 && gatev[b]) atomicAdd(out, sb[0]);
}

}  // namespace

extern "C" void kernel_launch(void* const* d_in, const int* in_sizes, int n_in,
                              void* d_out, int out_size, void* d_ws, size_t ws_size,
                              hipStream_t stream) {
  const float* meta = (const float*)d_in[0];
  const int* thing  = (const int*)d_in[1];
  const int* label  = (const int*)d_in[2];
  float* out = (float*)d_out;

  char* ws = (char*)d_ws;
  size_t off = 0;
  uint8_t* wn = (uint8_t*)(ws + off); off += (size_t)Bb * Ll * Pp * Dd;  // 12.6 MB fp8
  int* qpos  = (int*)(ws + off); off += (size_t)Bb * Ll * Pp * 4;
  int* negc  = (int*)(ws + off); off += (size_t)Bb * Pp * 4;
  int* qidx  = (int*)(ws + off); off += (size_t)Bb * Pp * 4;
  int* Kv    = (int*)(ws + off); off += 64;
  int* gatev = (int*)(ws + off); off += 64;
  float* rowsum_g = (float*)(ws + off); off += (size_t)Bb * Ll * Pp * 4;
  float* zp_g     = (float*)(ws + off); off += (size_t)Bb * Ll * Pp * 4;
  float* zl_g     = (float*)(ws + off); off += (size_t)Bb * Ll * Pp * 4;

  const int nb_prep = NB_NORM + NB_ROW + Bb + 48 + 1;  // 14345
  prep_k<<<nb_prep, 256, 0, stream>>>(meta, thing, label, wn, qpos, negc, qidx,
                                      Kv, gatev, rowsum_g, out);
  zpzl_k<<<(Bb * Ll * Pp) / 4, 256, 0, stream>>>(wn, qpos, qidx, zp_g, zl_g);
  gemm_loss_k<<<1728, 256, 0, stream>>>(wn, thing, label, rowsum_g);
  finalize_k<<<Bb * Ll, 256, 0, stream>>>(rowsum_g, zp_g, zl_g, negc, thing, Kv, gatev, out);
}